// Round 1
// baseline (203.889 us; speedup 1.0000x reference)
//
#include <hip/hip_runtime.h>

// Problem constants (fixed by reference setup_inputs):
//   y:   (B=32, K=64, n1=4, n2=8, n3=8) fp32
//   W1d: (K, 1, b1=256, 1, 1)  -> w1[k][i],  i in [0,256)
//   W2d: (K, 1, 1, b2=4, b3=4) -> w2[k][j][l]
//   out: (B, 1, n1*b1=1024, n2*b2=32, n3*b3=32) fp32
// out[b, x*256+i, yy*4+j, z*4+l] = sum_k y[b,k,x,yy,z] * w1[k,i] * w2[k,j,l]
//
// Per-(b,x,yy) this is a rank-64 GEMM: out[i, c] = sum_k w1[k,i] * s[k,c]
// with c = j*32 + z*4 + l (the 128 contiguous output floats per i-row)
// and s[k,c] = y[b,k,x,yy,z] * w2[k,j,l] built once per block in LDS.

#define KK 64

__global__ __launch_bounds__(256, 3)
void backproj_kernel(const float* __restrict__ y,
                     const float* __restrict__ w1,
                     const float* __restrict__ w2,
                     float* __restrict__ out)
{
    __shared__ float y_s[KK * 8];     //  2 KiB: y[k][z] slice
    __shared__ float s_s[KK * 128];   // 32 KiB: s[k][c]
    __shared__ float w1c[KK * 64];    // 16 KiB: w1 chunk [k][ii]

    const int bid    = blockIdx.x;
    const int ichunk = bid & 3;          // 4 chunks of 64 over b1=256
    const int yy     = (bid >> 2) & 7;
    const int x      = (bid >> 5) & 3;
    const int b      = bid >> 7;

    const int tid   = threadIdx.x;
    const int c     = tid & 127;   // j*32 + z*4 + l  (output-contiguous)
    const int ihalf = tid >> 7;    // 0/1 -> which 32 i's this thread owns

    // ---- stage y slice: y[b,k,x,yy,z] = y[b*16384 + k*256 + x*64 + yy*8 + z]
    {
        const float* ybase = y + (size_t)b * 16384 + x * 64 + yy * 8;
        for (int idx = tid; idx < KK * 8; idx += 256) {
            int k = idx >> 3, z = idx & 7;
            y_s[idx] = ybase[k * 256 + z];
        }
    }
    // ---- stage w1 chunk: w1c[k][ii] = w1[k*256 + ichunk*64 + ii]
    {
        const float* wbase = w1 + ichunk * 64;
        for (int idx = tid; idx < KK * 64; idx += 256) {
            int k = idx >> 6, ii = idx & 63;
            w1c[idx] = wbase[k * 256 + ii];
        }
    }
    __syncthreads();

    // ---- build s[k][c] = y[k][z] * w2[k][j*4+l]
    for (int idx = tid; idx < KK * 128; idx += 256) {
        int k = idx >> 7, cc = idx & 127;
        int j = cc >> 5, zl = cc & 31;
        int z = zl >> 2, l = zl & 3;
        s_s[idx] = y_s[k * 8 + z] * w2[k * 16 + j * 4 + l];
    }
    __syncthreads();

    // ---- K-loop: acc[ii] += w1c[k][ihalf*32+ii] * s[k][c]
    float acc[32];
    #pragma unroll
    for (int ii = 0; ii < 32; ++ii) acc[ii] = 0.f;

    #pragma unroll 8
    for (int k = 0; k < KK; ++k) {
        const float sv = s_s[k * 128 + c];                       // per-lane, stride-1
        const float4* wrow = (const float4*)&w1c[k * 64 + ihalf * 32]; // wave-uniform
        #pragma unroll
        for (int q = 0; q < 8; ++q) {
            float4 wv = wrow[q];
            acc[q * 4 + 0] += wv.x * sv;
            acc[q * 4 + 1] += wv.y * sv;
            acc[q * 4 + 2] += wv.z * sv;
            acc[q * 4 + 3] += wv.w * sv;
        }
    }

    // ---- store: addr = (b*1024 + x*256 + ichunk*64 + ihalf*32 + ii)*1024 + yy*128 + c
    float* obase = out
        + (size_t)(b * 1024 + x * 256 + ichunk * 64 + ihalf * 32) * 1024
        + yy * 128 + c;
    #pragma unroll
    for (int ii = 0; ii < 32; ++ii)
        obase[ii * 1024] = acc[ii];   // wave writes 256 B contiguous
}

extern "C" void kernel_launch(void* const* d_in, const int* in_sizes, int n_in,
                              void* d_out, int out_size, void* d_ws, size_t ws_size,
                              hipStream_t stream) {
    const float* y  = (const float*)d_in[0];
    const float* w1 = (const float*)d_in[1];   // (64, 256)
    const float* w2 = (const float*)d_in[2];   // (64, 16)
    float* out = (float*)d_out;

    // grid = B * n1 * n2 * (b1/64) = 32*4*8*4 = 4096 blocks
    backproj_kernel<<<dim3(4096), dim3(256), 0, stream>>>(y, w1, w2, out);
}

// Round 2
// 171.894 us; speedup vs baseline: 1.1861x; 1.1861x over previous
//
#include <hip/hip_runtime.h>

// y:   (B=32, K=64, n1=4, n2=8, n3=8) fp32
// W1d: (K,1,256,1,1) -> w1[k][i]
// W2d: (K,1,1,4,4)   -> w2[k][j][l]
// out[b, x*256+i, yy*4+j, z*4+l] = sum_k y[b,k,x,yy,z] * w1[k,i] * w2[k,j,l]
//
// Per-(b,x,yy,ichunk): out[i, c] = sum_k w1[k, ichunk*64+i] * (y[k,z] * w2[k,j,l])
// with c = j*32 + z*4 + l in [0,128). Block computes 64 i x 128 c.
// Thread (tx=tid&31, ty=tid>>5) computes i in [ty*8, ty*8+8), c in [tx*4, tx*4+4).
// tx*4 = j*32 + z*4  =>  j = tx>>3, z = tx&7  (l = 0..3 inside the float4).
//
// Inner loop per k (all LDS reads are broadcast / distinct-bank, conflict-free):
//   1x ds_read_b32  y_s[k][z]        (8 distinct addrs, 8 banks)
//   1x ds_read_b128 w2_s[k][j*4]     (4 distinct addrs)
//   2x ds_read_b128 w1c[k][ty*8]     (2 distinct addrs per wave)
//   4 v_mul (form s in regs) + 32 v_fma

#define KK 64

__global__ __launch_bounds__(256, 4)
void backproj_kernel(const float* __restrict__ y,
                     const float* __restrict__ w1,
                     const float* __restrict__ w2,
                     float* __restrict__ out)
{
    __shared__ float y_s[KK * 8];      //  2 KiB
    __shared__ float4 w2_s[KK * 4];    //  4 KiB
    __shared__ float4 w1c[KK * 16];    // 16 KiB  (64 i per block)

    const int bid    = blockIdx.x;
    const int ichunk = bid & 3;
    const int yy     = (bid >> 2) & 7;
    const int x      = (bid >> 5) & 3;
    const int b      = bid >> 7;

    const int tid = threadIdx.x;
    const int tx  = tid & 31;     // c4 = tx*4
    const int ty  = tid >> 5;     // i8 = ty*8
    const int j   = tx >> 3;
    const int z   = tx & 7;

    // ---- stage y slice (512 floats = 128 float4; y rows are 8 contiguous floats)
    {
        const float* ybase = y + (size_t)b * 16384 + x * 64 + yy * 8;
        if (tid < 128) {
            int k = tid >> 1, h = tid & 1;
            ((float4*)y_s)[tid] = ((const float4*)(ybase + k * 256))[h];
        }
    }
    // ---- stage w2 (1024 floats = 256 float4, contiguous)
    w2_s[tid] = ((const float4*)w2)[tid];
    // ---- stage w1 chunk (4096 floats = 1024 float4)
    {
        const float* wbase = w1 + ichunk * 64;
        #pragma unroll
        for (int r = 0; r < 4; ++r) {
            int idx = r * 256 + tid;          // [0,1024)
            int k = idx >> 4, q = idx & 15;
            w1c[idx] = ((const float4*)(wbase + k * 256))[q];
        }
    }
    __syncthreads();

    float4 acc[8];
    #pragma unroll
    for (int ii = 0; ii < 8; ++ii) acc[ii] = make_float4(0.f, 0.f, 0.f, 0.f);

    const int w1base = ty * 2;                // float4 index within a k-row of 16

    #pragma unroll 8
    for (int k = 0; k < KK; ++k) {
        const float  yv  = y_s[k * 8 + z];
        const float4 w2v = w2_s[k * 4 + j];
        float4 sv;
        sv.x = yv * w2v.x; sv.y = yv * w2v.y; sv.z = yv * w2v.z; sv.w = yv * w2v.w;

        const float4 wa = w1c[k * 16 + w1base + 0];   // i8+0..3
        const float4 wb = w1c[k * 16 + w1base + 1];   // i8+4..7

        acc[0].x += wa.x * sv.x; acc[0].y += wa.x * sv.y; acc[0].z += wa.x * sv.z; acc[0].w += wa.x * sv.w;
        acc[1].x += wa.y * sv.x; acc[1].y += wa.y * sv.y; acc[1].z += wa.y * sv.z; acc[1].w += wa.y * sv.w;
        acc[2].x += wa.z * sv.x; acc[2].y += wa.z * sv.y; acc[2].z += wa.z * sv.z; acc[2].w += wa.z * sv.w;
        acc[3].x += wa.w * sv.x; acc[3].y += wa.w * sv.y; acc[3].z += wa.w * sv.z; acc[3].w += wa.w * sv.w;
        acc[4].x += wb.x * sv.x; acc[4].y += wb.x * sv.y; acc[4].z += wb.x * sv.z; acc[4].w += wb.x * sv.w;
        acc[5].x += wb.y * sv.x; acc[5].y += wb.y * sv.y; acc[5].z += wb.y * sv.z; acc[5].w += wb.y * sv.w;
        acc[6].x += wb.z * sv.x; acc[6].y += wb.z * sv.y; acc[6].z += wb.z * sv.z; acc[6].w += wb.z * sv.w;
        acc[7].x += wb.w * sv.x; acc[7].y += wb.w * sv.y; acc[7].z += wb.w * sv.z; acc[7].w += wb.w * sv.w;
    }

    // ---- store: thread writes 8 rows x 4 consecutive floats (dwordx4)
    float* obase = out
        + (size_t)(b * 1024 + x * 256 + ichunk * 64 + ty * 8) * 1024
        + yy * 128 + tx * 4;
    #pragma unroll
    for (int ii = 0; ii < 8; ++ii)
        *(float4*)(obase + ii * 1024) = acc[ii];
}

extern "C" void kernel_launch(void* const* d_in, const int* in_sizes, int n_in,
                              void* d_out, int out_size, void* d_ws, size_t ws_size,
                              hipStream_t stream) {
    const float* y  = (const float*)d_in[0];
    const float* w1 = (const float*)d_in[1];   // (64, 256)
    const float* w2 = (const float*)d_in[2];   // (64, 16)
    float* out = (float*)d_out;

    backproj_kernel<<<dim3(4096), dim3(256), 0, stream>>>(y, w1, w2, out);
}